// Round 1
// baseline (637.663 us; speedup 1.0000x reference)
//
#include <hip/hip_runtime.h>
#include <math.h>

#define N_NODES 20000
#define N_EDGES 320000
#define ET (N_EDGES + N_NODES)   // edges + self loops
#define IN_CH 256
#define HID 128
#define HEADS 4
#define OUT_CH 16
#define N_GRAPHS 128
#define NEG_SLOPE 0.2f

// ---------------- fp32 tiled GEMM: C[M,N] = A[M,K] @ B[K,N] ----------------
template<int BM,int BN,int BK>
__global__ __launch_bounds__(256) void gemm_f32(const float* __restrict__ A,
    const float* __restrict__ B, float* __restrict__ C, int M, int N, int K) {
  __shared__ float As[BK][BM];
  __shared__ float Bs[BK][BN];
  const int bm = blockIdx.y * BM, bn = blockIdx.x * BN;
  const int tid = threadIdx.x;
  const int tx = tid % (BN/4), ty = tid / (BN/4);
  float acc[4][4] = {};
  for (int k0 = 0; k0 < K; k0 += BK) {
    for (int i = tid; i < BM*BK; i += 256) {
      int r = i / BK, c = i % BK;
      int gr = bm + r;
      As[c][r] = (gr < M) ? A[(size_t)gr*K + k0 + c] : 0.f;
    }
    for (int i = tid; i < BK*BN; i += 256) {
      int r = i / BN, c = i % BN;
      Bs[r][c] = B[(size_t)(k0+r)*N + bn + c];
    }
    __syncthreads();
    #pragma unroll
    for (int kk = 0; kk < BK; ++kk) {
      float4 a4 = *(const float4*)&As[kk][ty*4];
      float4 b4 = *(const float4*)&Bs[kk][tx*4];
      float a[4] = {a4.x,a4.y,a4.z,a4.w};
      float b[4] = {b4.x,b4.y,b4.z,b4.w};
      #pragma unroll
      for (int i=0;i<4;i++)
        #pragma unroll
        for (int j=0;j<4;j++)
          acc[i][j] += a[i]*b[j];
    }
    __syncthreads();
  }
  #pragma unroll
  for (int i=0;i<4;i++) {
    int gr = bm + ty*4 + i;
    if (gr < M) {
      float4* cp = (float4*)&C[(size_t)gr*N + bn + tx*4];
      *cp = make_float4(acc[i][0],acc[i][1],acc[i][2],acc[i][3]);
    }
  }
}

// -------- attention coefficients: a_src[n,h]=dot(h[n,h,:],as[h,:]) ---------
// one wave (64 lanes) per node; 2 channels per lane per head
__global__ __launch_bounds__(256) void att_heads(const float* __restrict__ h,
    const float* __restrict__ as, const float* __restrict__ ad,
    float* __restrict__ outs, float* __restrict__ outd,
    int n_nodes, int heads, int C) {
  int wave = threadIdx.x >> 6;
  int lane = threadIdx.x & 63;
  int node = blockIdx.x * (blockDim.x >> 6) + wave;
  if (node >= n_nodes) return;
  for (int hd = 0; hd < heads; ++hd) {
    int c = lane * 2;
    const float2 hv = *(const float2*)&h[(size_t)node*heads*C + hd*C + c];
    float ps = hv.x*as[hd*C+c] + hv.y*as[hd*C+c+1];
    float pd = hv.x*ad[hd*C+c] + hv.y*ad[hd*C+c+1];
    #pragma unroll
    for (int o = 32; o > 0; o >>= 1) {
      ps += __shfl_down(ps, o);
      pd += __shfl_down(pd, o);
    }
    if (lane == 0) { outs[node*heads+hd] = ps; outd[node*heads+hd] = pd; }
  }
}

// ---------------- CSR build (by destination), incl. self loops -------------
__global__ void hist_kernel(const int* __restrict__ dst, int* __restrict__ cnt) {
  int e = blockIdx.x*blockDim.x + threadIdx.x;
  if (e >= ET) return;
  int d = (e < N_EDGES) ? dst[e] : (e - N_EDGES);
  atomicAdd(&cnt[d], 1);
}

__global__ __launch_bounds__(1024) void scan_kernel(const int* __restrict__ cnt,
    int* __restrict__ offs, int* __restrict__ cursor, int n) {
  __shared__ int sdata[1024];
  __shared__ int carry_s;
  int tid = threadIdx.x;
  if (tid == 0) carry_s = 0;
  __syncthreads();
  int nchunks = (n + 1023) / 1024;
  for (int ch = 0; ch < nchunks; ++ch) {
    int i = ch*1024 + tid;
    int v = (i < n) ? cnt[i] : 0;
    sdata[tid] = v;
    __syncthreads();
    for (int off = 1; off < 1024; off <<= 1) {
      int t = (tid >= off) ? sdata[tid-off] : 0;
      __syncthreads();
      sdata[tid] += t;
      __syncthreads();
    }
    int incl = sdata[tid];
    int excl = incl - v;
    int carry = carry_s;
    if (i < n) { offs[i] = carry + excl; cursor[i] = carry + excl; }
    __syncthreads();
    if (tid == 1023) carry_s = carry + incl;
    __syncthreads();
  }
  if (tid == 0) offs[n] = carry_s;
}

__global__ void fill_kernel(const int* __restrict__ src, const int* __restrict__ dst,
                            int* __restrict__ cursor, int* __restrict__ csr) {
  int e = blockIdx.x*blockDim.x + threadIdx.x;
  if (e >= ET) return;
  int s, d;
  if (e < N_EDGES) { s = src[e]; d = dst[e]; } else { s = d = e - N_EDGES; }
  int pos = atomicAdd(&cursor[d], 1);
  csr[pos] = s;
}

// --------- layer-1 aggregation: block per dst node, 256 thr × 2 ch ---------
__global__ __launch_bounds__(256) void agg1_kernel(
    const float* __restrict__ h1, const float* __restrict__ a1s,
    const float* __restrict__ a1d, const int* __restrict__ offs,
    const int* __restrict__ csr, const float* __restrict__ b1,
    float* __restrict__ out) {
  int n = blockIdx.x;
  int tid = threadIdx.x;
  int head = tid >> 6;          // 64 threads (=128 ch) per head
  int c0 = tid * 2;
  float ad_n = a1d[n*HEADS + head];
  float accx = 0.f, accy = 0.f, den = 0.f;
  int e0 = offs[n], e1 = offs[n+1];
  for (int e = e0; e < e1; ++e) {
    int s = csr[e];
    float aa = a1s[s*HEADS + head] + ad_n;
    aa = (aa > 0.f) ? aa : NEG_SLOPE*aa;
    float al = expf(aa);        // no max-shift needed: |aa| <~ 15 in fp32
    float2 hv = *(const float2*)&h1[(size_t)s*(HEADS*HID) + c0];
    accx += al*hv.x; accy += al*hv.y;
    den += al;
  }
  float inv = 1.f / den;        // self-loop guarantees den > 0
  float o0 = fmaxf(accx*inv + b1[c0],   0.f);   // bias then ReLU
  float o1 = fmaxf(accy*inv + b1[c0+1], 0.f);
  *(float2*)&out[(size_t)n*(HEADS*HID) + c0] = make_float2(o0, o1);
}

// --------- layer-2 aggregation: block per dst node, 128 thr × 1 ch ---------
__global__ __launch_bounds__(128) void agg2_kernel(
    const float* __restrict__ h2, const float* __restrict__ a2s,
    const float* __restrict__ a2d, const int* __restrict__ offs,
    const int* __restrict__ csr, const float* __restrict__ b2,
    float* __restrict__ out) {
  int n = blockIdx.x;
  int c = threadIdx.x;
  float ad_n = a2d[n];
  float acc = 0.f, den = 0.f;
  int e0 = offs[n], e1 = offs[n+1];
  for (int e = e0; e < e1; ++e) {
    int s = csr[e];
    float aa = a2s[s] + ad_n;
    aa = (aa > 0.f) ? aa : NEG_SLOPE*aa;
    float al = expf(aa);
    acc += al * h2[(size_t)s*HID + c];
    den += al;
  }
  out[(size_t)n*HID + c] = acc/den + b2[c];     // no ReLU after layer 2
}

// ------------------------- global mean pool ---------------------------------
__global__ void pool_kernel(const float* __restrict__ h, const int* __restrict__ batch,
                            float* __restrict__ pooled, float* __restrict__ cntg) {
  int idx = blockIdx.x*blockDim.x + threadIdx.x;
  if (idx >= N_NODES*HID) return;
  int n = idx >> 7, c = idx & 127;
  int g = batch[n];
  atomicAdd(&pooled[g*HID + c], h[idx]);
  if (c == 0) atomicAdd(&cntg[g], 1.0f);
}

// ------------------------------ MLP head ------------------------------------
__global__ __launch_bounds__(128) void mlp_kernel(const float* __restrict__ pooled,
    const float* __restrict__ cntg, const float* __restrict__ Wm1,
    const float* __restrict__ bm1, const float* __restrict__ Wm2,
    const float* __restrict__ bm2, float* __restrict__ outp) {
  __shared__ float pl[HID];
  __shared__ float z[HID];
  int g = blockIdx.x, j = threadIdx.x;
  float inv = 1.f / fmaxf(cntg[g], 1.f);
  pl[j] = pooled[g*HID + j] * inv;
  __syncthreads();
  float s = bm1[j];
  for (int k = 0; k < HID; ++k) s += pl[k]*Wm1[k*HID + j];
  z[j] = fmaxf(s, 0.f);
  __syncthreads();
  if (j < OUT_CH) {
    float o = bm2[j];
    for (int k = 0; k < HID; ++k) o += z[k]*Wm2[k*OUT_CH + j];
    outp[g*OUT_CH + j] = o;
  }
}

extern "C" void kernel_launch(void* const* d_in, const int* in_sizes, int n_in,
                              void* d_out, int out_size, void* d_ws, size_t ws_size,
                              hipStream_t stream) {
  const float* x    = (const float*)d_in[0];
  const int*   ei   = (const int*)d_in[1];     // [2, E] int
  const int*   batch= (const int*)d_in[2];
  const float* W1   = (const float*)d_in[3];
  const float* as1  = (const float*)d_in[4];
  const float* ad1  = (const float*)d_in[5];
  const float* b1   = (const float*)d_in[6];
  const float* W2   = (const float*)d_in[7];
  const float* as2  = (const float*)d_in[8];
  const float* ad2  = (const float*)d_in[9];
  const float* b2   = (const float*)d_in[10];
  const float* Wm1  = (const float*)d_in[11];
  const float* bm1  = (const float*)d_in[12];
  const float* Wm2  = (const float*)d_in[13];
  const float* bm2  = (const float*)d_in[14];
  float* outp = (float*)d_out;
  const int* srcp = ei;
  const int* dstp = ei + N_EDGES;

  // ---- workspace carve-up (~106 MB) ----
  char* p = (char*)d_ws;
  auto alloc = [&](size_t bytes) {
    char* r = p; p += (bytes + 255) & ~(size_t)255; return r;
  };
  float* h1    = (float*)alloc((size_t)N_NODES*HEADS*HID*4);   // 40.96 MB
  float* h1r   = (float*)alloc((size_t)N_NODES*HEADS*HID*4);   // 40.96 MB
  float* h2    = (float*)alloc((size_t)N_NODES*HID*4);         // 10.24 MB
  float* h2a   = (float*)alloc((size_t)N_NODES*HID*4);         // 10.24 MB
  float* a1s   = (float*)alloc((size_t)N_NODES*HEADS*4);
  float* a1d   = (float*)alloc((size_t)N_NODES*HEADS*4);
  float* a2s   = (float*)alloc((size_t)N_NODES*4);
  float* a2d   = (float*)alloc((size_t)N_NODES*4);
  int*   cnt   = (int*)alloc((size_t)N_NODES*4);
  int*   offs  = (int*)alloc((size_t)(N_NODES+1)*4);
  int*   cursor= (int*)alloc((size_t)N_NODES*4);
  int*   csr   = (int*)alloc((size_t)ET*4);
  float* pooled= (float*)alloc((size_t)N_GRAPHS*HID*4);
  float* cntg  = (float*)alloc((size_t)N_GRAPHS*4);

  hipMemsetAsync(cnt,    0, (size_t)N_NODES*4,      stream);
  hipMemsetAsync(pooled, 0, (size_t)N_GRAPHS*HID*4, stream);
  hipMemsetAsync(cntg,   0, (size_t)N_GRAPHS*4,     stream);

  // layer 1 projection: h1 = x @ W1    [20000,256]@[256,512]
  dim3 g1grid((HEADS*HID)/64, (N_NODES+63)/64);
  gemm_f32<64,64,16><<<g1grid, 256, 0, stream>>>(x, W1, h1, N_NODES, HEADS*HID, IN_CH);

  att_heads<<<(N_NODES+3)/4, 256, 0, stream>>>(h1, as1, ad1, a1s, a1d, N_NODES, HEADS, HID);

  // CSR by dst (shared by both layers)
  hist_kernel<<<(ET+255)/256, 256, 0, stream>>>(dstp, cnt);
  scan_kernel<<<1, 1024, 0, stream>>>(cnt, offs, cursor, N_NODES);
  fill_kernel<<<(ET+255)/256, 256, 0, stream>>>(srcp, dstp, cursor, csr);

  agg1_kernel<<<N_NODES, 256, 0, stream>>>(h1, a1s, a1d, offs, csr, b1, h1r);

  // layer 2 projection: h2 = h1r @ W2  [20000,512]@[512,128]
  dim3 g2grid(HID/64, (N_NODES+63)/64);
  gemm_f32<64,64,16><<<g2grid, 256, 0, stream>>>(h1r, W2, h2, N_NODES, HID, HEADS*HID);

  att_heads<<<(N_NODES+3)/4, 256, 0, stream>>>(h2, as2, ad2, a2s, a2d, N_NODES, 1, HID);

  agg2_kernel<<<N_NODES, 128, 0, stream>>>(h2, a2s, a2d, offs, csr, b2, h2a);

  pool_kernel<<<(N_NODES*HID+255)/256, 256, 0, stream>>>(h2a, batch, pooled, cntg);

  mlp_kernel<<<N_GRAPHS, 128, 0, stream>>>(pooled, cntg, Wm1, bm1, Wm2, bm2, outp);
}

// Round 2
// 430.827 us; speedup vs baseline: 1.4801x; 1.4801x over previous
//
#include <hip/hip_runtime.h>
#include <math.h>

#define N_NODES 20000
#define N_EDGES 320000
#define ET (N_EDGES + N_NODES)   // edges + self loops
#define IN_CH 256
#define HID 128
#define HEADS 4
#define OUT_CH 16
#define N_GRAPHS 128
#define NEG_SLOPE 0.2f

typedef _Float16 f16x8 __attribute__((ext_vector_type(8)));
typedef _Float16 f16x4 __attribute__((ext_vector_type(4)));
typedef _Float16 f16x2 __attribute__((ext_vector_type(2)));
typedef float f32x4 __attribute__((ext_vector_type(4)));

// =============== fp16 MFMA GEMM: C[M,N] = A[M,K] @ Bt[N,K]^T ================
// A row-major fp16 [M,K]; Bt row-major fp16 [N,K] (i.e. B transposed);
// C fp16 [M,N]. 128x128 tile, BK=32, 4 waves of 4x4 16x16x32 MFMA tiles.
#define LDT 40   // padded LDS stride in f16 (80 B = 16B-aligned, 2-way max conflict)
__global__ __launch_bounds__(256) void gemm_f16(const _Float16* __restrict__ A,
    const _Float16* __restrict__ Bt, _Float16* __restrict__ C,
    int M, int N, int K) {
  __shared__ _Float16 As[128 * LDT];
  __shared__ _Float16 Bs[128 * LDT];
  const int bm = blockIdx.y * 128, bn = blockIdx.x * 128;
  const int tid = threadIdx.x;
  const int lane = tid & 63, wv = tid >> 6;
  const int wr = wv >> 1, wc = wv & 1;
  const int r0 = tid >> 2, seg = tid & 3;   // staging: 4 thr/row, 8 f16 each
  const int m_lo = lane & 15, koff = (lane >> 4) * 8, rq = lane >> 4;
  f32x4 acc[4][4] = {};
  for (int k0 = 0; k0 < K; k0 += 32) {
    const int4 zero4 = {0, 0, 0, 0};
    int gr0 = bm + r0, gr1 = bm + r0 + 64;
    int4 av0 = (gr0 < M) ? *(const int4*)(A + (size_t)gr0 * K + k0 + seg * 8) : zero4;
    int4 av1 = (gr1 < M) ? *(const int4*)(A + (size_t)gr1 * K + k0 + seg * 8) : zero4;
    int4 bv0 = *(const int4*)(Bt + (size_t)(bn + r0) * K + k0 + seg * 8);
    int4 bv1 = *(const int4*)(Bt + (size_t)(bn + r0 + 64) * K + k0 + seg * 8);
    __syncthreads();
    *(int4*)(As + r0 * LDT + seg * 8) = av0;
    *(int4*)(As + (r0 + 64) * LDT + seg * 8) = av1;
    *(int4*)(Bs + r0 * LDT + seg * 8) = bv0;
    *(int4*)(Bs + (r0 + 64) * LDT + seg * 8) = bv1;
    __syncthreads();
    f16x8 af[4], bf[4];
    #pragma unroll
    for (int i = 0; i < 4; i++)
      af[i] = *(const f16x8*)(As + (wr * 64 + i * 16 + m_lo) * LDT + koff);
    #pragma unroll
    for (int j = 0; j < 4; j++)
      bf[j] = *(const f16x8*)(Bs + (wc * 64 + j * 16 + m_lo) * LDT + koff);
    #pragma unroll
    for (int i = 0; i < 4; i++)
      #pragma unroll
      for (int j = 0; j < 4; j++)
        acc[i][j] = __builtin_amdgcn_mfma_f32_16x16x32_f16(af[i], bf[j], acc[i][j], 0, 0, 0);
  }
  // C/D layout: col = lane&15, row = (lane>>4)*4 + reg  [m89-verified]
  #pragma unroll
  for (int i = 0; i < 4; i++) {
    #pragma unroll
    for (int r = 0; r < 4; r++) {
      int grow = bm + wr * 64 + i * 16 + rq * 4 + r;
      if (grow < M) {
        #pragma unroll
        for (int j = 0; j < 4; j++) {
          int gcol = bn + wc * 64 + j * 16 + m_lo;
          C[(size_t)grow * N + gcol] = (_Float16)acc[i][j][r];
        }
      }
    }
  }
}

// ============ weight prep: transpose to [N,K] fp16, fold att vectors ========
__global__ void transpose_f16(const float* __restrict__ B, _Float16* __restrict__ Bt,
                              int K, int N) {
  int idx = blockIdx.x * blockDim.x + threadIdx.x;
  if (idx >= K * N) return;
  int n = idx / K, k = idx % K;
  Bt[idx] = (_Float16)B[(size_t)k * N + n];
}

// wt1[j][i], j=0..3: W1@as1 per head; j=4..7: W1@ad1 per head. i=0..255.
__global__ void wtilde1_kernel(const float* __restrict__ W1, const float* __restrict__ as1,
                               const float* __restrict__ ad1, float* __restrict__ wt1) {
  int j = blockIdx.x, i = threadIdx.x;
  int sd = j >> 2, h = j & 3;
  const float* av = sd ? ad1 : as1;
  float s = 0.f;
  for (int c = 0; c < HID; ++c)
    s += W1[(size_t)i * (HEADS * HID) + h * HID + c] * av[h * HID + c];
  wt1[j * IN_CH + i] = s;
}

// wt2[0][c]=dot(W2 row c, as2); wt2[1][c]=dot(W2 row c, ad2). c=0..511.
__global__ void wtilde2_kernel(const float* __restrict__ W2, const float* __restrict__ as2,
                               const float* __restrict__ ad2, float* __restrict__ wt2) {
  int c = blockIdx.x * blockDim.x + threadIdx.x;
  if (c >= HEADS * HID) return;
  float s = 0.f, d = 0.f;
  for (int j = 0; j < HID; ++j) {
    float w = W2[(size_t)c * HID + j];
    s += w * as2[j];
    d += w * ad2[j];
  }
  wt2[c] = s;
  wt2[HEADS * HID + c] = d;
}

// ====== x -> fp16 conversion fused with a1s/a1d = x @ wt1 (wave per node) ===
__global__ __launch_bounds__(256) void conv_x(const float* __restrict__ x,
    const float* __restrict__ wt1, _Float16* __restrict__ xb,
    float* __restrict__ a1s, float* __restrict__ a1d) {
  int node = blockIdx.x * 4 + (threadIdx.x >> 6);
  int lane = threadIdx.x & 63;
  if (node >= N_NODES) return;
  int c = lane * 4;
  float4 xv = *(const float4*)(x + (size_t)node * IN_CH + c);
  *(f16x4*)(xb + (size_t)node * IN_CH + c) =
      f16x4{(_Float16)xv.x, (_Float16)xv.y, (_Float16)xv.z, (_Float16)xv.w};
  float p[8];
  #pragma unroll
  for (int jj = 0; jj < 8; ++jj) {
    float4 w = *(const float4*)(wt1 + jj * IN_CH + c);
    p[jj] = xv.x * w.x + xv.y * w.y + xv.z * w.z + xv.w * w.w;
  }
  #pragma unroll
  for (int o = 32; o > 0; o >>= 1)
    #pragma unroll
    for (int jj = 0; jj < 8; ++jj) p[jj] += __shfl_down(p[jj], o);
  if (lane == 0) {
    #pragma unroll
    for (int h = 0; h < 4; ++h) {
      a1s[node * HEADS + h] = p[h];
      a1d[node * HEADS + h] = p[4 + h];
    }
  }
}

// ================= CSR build (by destination), incl. self loops =============
__global__ void hist_kernel(const int* __restrict__ dst, int* __restrict__ cnt) {
  int e = blockIdx.x * blockDim.x + threadIdx.x;
  if (e >= ET) return;
  int d = (e < N_EDGES) ? dst[e] : (e - N_EDGES);
  atomicAdd(&cnt[d], 1);
}

__global__ __launch_bounds__(1024) void scan_kernel(const int* __restrict__ cnt,
    int* __restrict__ offs, int* __restrict__ cursor, int n) {
  __shared__ int sdata[1024];
  __shared__ int carry_s;
  int tid = threadIdx.x;
  if (tid == 0) carry_s = 0;
  __syncthreads();
  int nchunks = (n + 1023) / 1024;
  for (int ch = 0; ch < nchunks; ++ch) {
    int i = ch * 1024 + tid;
    int v = (i < n) ? cnt[i] : 0;
    sdata[tid] = v;
    __syncthreads();
    for (int off = 1; off < 1024; off <<= 1) {
      int t = (tid >= off) ? sdata[tid - off] : 0;
      __syncthreads();
      sdata[tid] += t;
      __syncthreads();
    }
    int incl = sdata[tid];
    int excl = incl - v;
    int carry = carry_s;
    if (i < n) { offs[i] = carry + excl; cursor[i] = carry + excl; }
    __syncthreads();
    if (tid == 1023) carry_s = carry + incl;
    __syncthreads();
  }
  if (tid == 0) offs[n] = carry_s;
}

__global__ void fill_kernel(const int* __restrict__ src, const int* __restrict__ dst,
                            int* __restrict__ cursor, int* __restrict__ csr) {
  int e = blockIdx.x * blockDim.x + threadIdx.x;
  if (e >= ET) return;
  int s, d;
  if (e < N_EDGES) { s = src[e]; d = dst[e]; } else { s = d = e - N_EDGES; }
  int pos = atomicAdd(&cursor[d], 1);
  csr[pos] = s;
}

__global__ void cnt_batch_kernel(const int* __restrict__ batch, float* __restrict__ cntg) {
  int i = blockIdx.x * blockDim.x + threadIdx.x;
  if (i >= N_NODES) return;
  atomicAdd(&cntg[batch[i]], 1.0f);
}

// ===== layer-1 aggregation (block/node, 2ch/thread) + relu + fp16 out ======
// also computes a2s/a2d = (relu(agg)+b1) . wt2 via block reduction
__global__ __launch_bounds__(256) void agg1_kernel(
    const _Float16* __restrict__ h1b, const float* __restrict__ a1s,
    const float* __restrict__ a1d, const int* __restrict__ offs,
    const int* __restrict__ csr, const float* __restrict__ b1,
    const float* __restrict__ wt2, _Float16* __restrict__ h1rb,
    float* __restrict__ a2s, float* __restrict__ a2d) {
  int n = blockIdx.x;
  int tid = threadIdx.x;
  int head = tid >> 6;          // 64 threads (=128 ch) per head
  int c0 = tid * 2;
  float ad_n = a1d[n * HEADS + head];
  float accx = 0.f, accy = 0.f, den = 0.f;
  int e0 = offs[n], e1 = offs[n + 1];
  for (int e = e0; e < e1; ++e) {
    int s = csr[e];
    float aa = a1s[s * HEADS + head] + ad_n;
    aa = (aa > 0.f) ? aa : NEG_SLOPE * aa;
    float al = expf(aa);        // |aa| <~ 15: no max-shift needed in fp32
    f16x2 hv = *(const f16x2*)(h1b + (size_t)s * (HEADS * HID) + c0);
    accx += al * (float)hv.x;
    accy += al * (float)hv.y;
    den += al;
  }
  float inv = 1.f / den;        // self-loop guarantees den > 0
  float o0 = fmaxf(accx * inv + b1[c0], 0.f);
  float o1 = fmaxf(accy * inv + b1[c0 + 1], 0.f);
  *(f16x2*)(h1rb + (size_t)n * (HEADS * HID) + c0) = f16x2{(_Float16)o0, (_Float16)o1};
  // layer-2 attention coefficients (algebraic fold: h2.as2 = h1r.(W2@as2))
  float ps = o0 * wt2[c0] + o1 * wt2[c0 + 1];
  float pd = o0 * wt2[HEADS * HID + c0] + o1 * wt2[HEADS * HID + c0 + 1];
  #pragma unroll
  for (int o = 32; o > 0; o >>= 1) { ps += __shfl_down(ps, o); pd += __shfl_down(pd, o); }
  __shared__ float rs[4], rd[4];
  int lane = tid & 63, wvi = tid >> 6;
  if (lane == 0) { rs[wvi] = ps; rd[wvi] = pd; }
  __syncthreads();
  if (tid == 0) a2s[n] = rs[0] + rs[1] + rs[2] + rs[3];
  if (tid == 1) a2d[n] = rd[0] + rd[1] + rd[2] + rd[3];
}

// ========== layer-2 aggregation fused with global mean-pool atomics ========
__global__ __launch_bounds__(128) void agg2_pool(
    const _Float16* __restrict__ h2b, const float* __restrict__ a2s,
    const float* __restrict__ a2d, const int* __restrict__ offs,
    const int* __restrict__ csr, const float* __restrict__ b2,
    const int* __restrict__ batch, float* __restrict__ pooled) {
  int n = blockIdx.x, c = threadIdx.x;
  float ad_n = a2d[n];
  float acc = 0.f, den = 0.f;
  int e0 = offs[n], e1 = offs[n + 1];
  for (int e = e0; e < e1; ++e) {
    int s = csr[e];
    float aa = a2s[s] + ad_n;
    aa = (aa > 0.f) ? aa : NEG_SLOPE * aa;
    float al = expf(aa);
    acc += al * (float)h2b[(size_t)s * HID + c];
    den += al;
  }
  float out = acc / den + b2[c];
  atomicAdd(&pooled[batch[n] * HID + c], out);
}

// ------------------------------ MLP head ------------------------------------
__global__ __launch_bounds__(128) void mlp_kernel(const float* __restrict__ pooled,
    const float* __restrict__ cntg, const float* __restrict__ Wm1,
    const float* __restrict__ bm1, const float* __restrict__ Wm2,
    const float* __restrict__ bm2, float* __restrict__ outp) {
  __shared__ float pl[HID];
  __shared__ float z[HID];
  int g = blockIdx.x, j = threadIdx.x;
  float inv = 1.f / fmaxf(cntg[g], 1.f);
  pl[j] = pooled[g * HID + j] * inv;
  __syncthreads();
  float s = bm1[j];
  for (int k = 0; k < HID; ++k) s += pl[k] * Wm1[k * HID + j];
  z[j] = fmaxf(s, 0.f);
  __syncthreads();
  if (j < OUT_CH) {
    float o = bm2[j];
    for (int k = 0; k < HID; ++k) o += z[k] * Wm2[k * OUT_CH + j];
    outp[g * OUT_CH + j] = o;
  }
}

extern "C" void kernel_launch(void* const* d_in, const int* in_sizes, int n_in,
                              void* d_out, int out_size, void* d_ws, size_t ws_size,
                              hipStream_t stream) {
  const float* x    = (const float*)d_in[0];
  const int*   ei   = (const int*)d_in[1];
  const int*   batch= (const int*)d_in[2];
  const float* W1   = (const float*)d_in[3];
  const float* as1  = (const float*)d_in[4];
  const float* ad1  = (const float*)d_in[5];
  const float* b1   = (const float*)d_in[6];
  const float* W2   = (const float*)d_in[7];
  const float* as2  = (const float*)d_in[8];
  const float* ad2  = (const float*)d_in[9];
  const float* b2   = (const float*)d_in[10];
  const float* Wm1  = (const float*)d_in[11];
  const float* bm1  = (const float*)d_in[12];
  const float* Wm2  = (const float*)d_in[13];
  const float* bm2  = (const float*)d_in[14];
  float* outp = (float*)d_out;
  const int* srcp = ei;
  const int* dstp = ei + N_EDGES;

  // ---- workspace carve-up (~59 MB) ----
  char* p = (char*)d_ws;
  auto alloc = [&](size_t bytes) {
    char* r = p; p += (bytes + 255) & ~(size_t)255; return r;
  };
  _Float16* xb   = (_Float16*)alloc((size_t)N_NODES * IN_CH * 2);        // 10.2 MB
  _Float16* h1b  = (_Float16*)alloc((size_t)N_NODES * HEADS * HID * 2);  // 20.5 MB
  _Float16* h1rb = (_Float16*)alloc((size_t)N_NODES * HEADS * HID * 2);  // 20.5 MB
  _Float16* h2b  = (_Float16*)alloc((size_t)N_NODES * HID * 2);          // 5.1 MB
  _Float16* W1T  = (_Float16*)alloc((size_t)(HEADS * HID) * IN_CH * 2);
  _Float16* W2T  = (_Float16*)alloc((size_t)HID * (HEADS * HID) * 2);
  float* wt1     = (float*)alloc(8 * IN_CH * 4);
  float* wt2     = (float*)alloc(2 * (HEADS * HID) * 4);
  float* a1s     = (float*)alloc((size_t)N_NODES * HEADS * 4);
  float* a1d     = (float*)alloc((size_t)N_NODES * HEADS * 4);
  float* a2s     = (float*)alloc((size_t)N_NODES * 4);
  float* a2d     = (float*)alloc((size_t)N_NODES * 4);
  int*   cnt     = (int*)alloc((size_t)N_NODES * 4);
  int*   offs    = (int*)alloc((size_t)(N_NODES + 1) * 4);
  int*   cursor  = (int*)alloc((size_t)N_NODES * 4);
  int*   csr     = (int*)alloc((size_t)ET * 4);
  float* pooled  = (float*)alloc((size_t)N_GRAPHS * HID * 4);
  float* cntg    = (float*)alloc((size_t)N_GRAPHS * 4);

  hipMemsetAsync(cnt,    0, (size_t)N_NODES * 4,        stream);
  hipMemsetAsync(pooled, 0, (size_t)N_GRAPHS * HID * 4, stream);
  hipMemsetAsync(cntg,   0, (size_t)N_GRAPHS * 4,       stream);

  // weight prep
  transpose_f16<<<(IN_CH * HEADS * HID + 255) / 256, 256, 0, stream>>>(W1, W1T, IN_CH, HEADS * HID);
  transpose_f16<<<(HEADS * HID * HID + 255) / 256, 256, 0, stream>>>(W2, W2T, HEADS * HID, HID);
  wtilde1_kernel<<<8, IN_CH, 0, stream>>>(W1, as1, ad1, wt1);
  wtilde2_kernel<<<2, 256, 0, stream>>>(W2, as2, ad2, wt2);

  // x -> fp16 + layer-1 attention coefficients
  conv_x<<<(N_NODES + 3) / 4, 256, 0, stream>>>(x, wt1, xb, a1s, a1d);

  // CSR by dst (shared by both layers) + per-graph node counts
  hist_kernel<<<(ET + 255) / 256, 256, 0, stream>>>(dstp, cnt);
  scan_kernel<<<1, 1024, 0, stream>>>(cnt, offs, cursor, N_NODES);
  fill_kernel<<<(ET + 255) / 256, 256, 0, stream>>>(srcp, dstp, cursor, csr);
  cnt_batch_kernel<<<(N_NODES + 255) / 256, 256, 0, stream>>>(batch, cntg);

  // layer 1: h1 = x @ W1   [20000,256]@[256,512]  (fp16 MFMA)
  gemm_f16<<<dim3((HEADS * HID) / 128, (N_NODES + 127) / 128), 256, 0, stream>>>(
      xb, W1T, h1b, N_NODES, HEADS * HID, IN_CH);

  agg1_kernel<<<N_NODES, 256, 0, stream>>>(h1b, a1s, a1d, offs, csr, b1, wt2, h1rb, a2s, a2d);

  // layer 2: h2 = h1r @ W2  [20000,512]@[512,128]  (fp16 MFMA)
  gemm_f16<<<dim3(HID / 128, (N_NODES + 127) / 128), 256, 0, stream>>>(
      h1rb, W2T, h2b, N_NODES, HID, HEADS * HID);

  agg2_pool<<<N_NODES, HID, 0, stream>>>(h2b, a2s, a2d, offs, csr, b2, batch, pooled);

  mlp_kernel<<<N_GRAPHS, HID, 0, stream>>>(pooled, cntg, Wm1, bm1, Wm2, bm2, outp);
}

// Round 3
// 376.995 us; speedup vs baseline: 1.6914x; 1.1428x over previous
//
#include <hip/hip_runtime.h>
#include <math.h>

#define N_NODES 20000
#define N_EDGES 320000
#define ET (N_EDGES + N_NODES)   // edges + self loops
#define IN_CH 256
#define HID 128
#define HEADS 4
#define OUT_CH 16
#define N_GRAPHS 128
#define NEG_SLOPE 0.2f

typedef _Float16 f16x8 __attribute__((ext_vector_type(8)));
typedef _Float16 f16x4 __attribute__((ext_vector_type(4)));
typedef _Float16 f16x2 __attribute__((ext_vector_type(2)));
typedef float f32x4 __attribute__((ext_vector_type(4)));

// =============== fp16 MFMA GEMM: C[M,N] = A[M,K] @ Bt[N,K]^T ================
// 128x128 tile, BK=32, 4 waves of 4x4 16x16x32 MFMA tiles.
#define LDT 40   // padded LDS stride in f16 (80 B: 16B-aligned, 2-way max conflict)
__global__ __launch_bounds__(256) void gemm_f16(const _Float16* __restrict__ A,
    const _Float16* __restrict__ Bt, _Float16* __restrict__ C,
    int M, int N, int K) {
  __shared__ _Float16 As[128 * LDT];
  __shared__ _Float16 Bs[128 * LDT];
  const int bm = blockIdx.y * 128, bn = blockIdx.x * 128;
  const int tid = threadIdx.x;
  const int lane = tid & 63, wv = tid >> 6;
  const int wr = wv >> 1, wc = wv & 1;
  const int r0 = tid >> 2, seg = tid & 3;
  const int m_lo = lane & 15, koff = (lane >> 4) * 8, rq = lane >> 4;
  f32x4 acc[4][4] = {};
  for (int k0 = 0; k0 < K; k0 += 32) {
    const int4 zero4 = {0, 0, 0, 0};
    int gr0 = bm + r0, gr1 = bm + r0 + 64;
    int4 av0 = (gr0 < M) ? *(const int4*)(A + (size_t)gr0 * K + k0 + seg * 8) : zero4;
    int4 av1 = (gr1 < M) ? *(const int4*)(A + (size_t)gr1 * K + k0 + seg * 8) : zero4;
    int4 bv0 = *(const int4*)(Bt + (size_t)(bn + r0) * K + k0 + seg * 8);
    int4 bv1 = *(const int4*)(Bt + (size_t)(bn + r0 + 64) * K + k0 + seg * 8);
    __syncthreads();
    *(int4*)(As + r0 * LDT + seg * 8) = av0;
    *(int4*)(As + (r0 + 64) * LDT + seg * 8) = av1;
    *(int4*)(Bs + r0 * LDT + seg * 8) = bv0;
    *(int4*)(Bs + (r0 + 64) * LDT + seg * 8) = bv1;
    __syncthreads();
    f16x8 af[4], bf[4];
    #pragma unroll
    for (int i = 0; i < 4; i++)
      af[i] = *(const f16x8*)(As + (wr * 64 + i * 16 + m_lo) * LDT + koff);
    #pragma unroll
    for (int j = 0; j < 4; j++)
      bf[j] = *(const f16x8*)(Bs + (wc * 64 + j * 16 + m_lo) * LDT + koff);
    #pragma unroll
    for (int i = 0; i < 4; i++)
      #pragma unroll
      for (int j = 0; j < 4; j++)
        acc[i][j] = __builtin_amdgcn_mfma_f32_16x16x32_f16(af[i], bf[j], acc[i][j], 0, 0, 0);
  }
  // C/D layout: col = lane&15, row = (lane>>4)*4 + reg
  #pragma unroll
  for (int i = 0; i < 4; i++)
    #pragma unroll
    for (int r = 0; r < 4; r++) {
      int grow = bm + wr * 64 + i * 16 + rq * 4 + r;
      if (grow < M)
        #pragma unroll
        for (int j = 0; j < 4; j++) {
          int gcol = bn + wc * 64 + j * 16 + m_lo;
          C[(size_t)grow * N + gcol] = (_Float16)acc[i][j][r];
        }
    }
}

// ============== fp16 MFMA GEMM, 128x64 tile (for N=128 layer-2) =============
__global__ __launch_bounds__(256) void gemm2_f16(const _Float16* __restrict__ A,
    const _Float16* __restrict__ Bt, _Float16* __restrict__ C,
    int M, int N, int K) {
  __shared__ _Float16 As[128 * LDT];
  __shared__ _Float16 Bs[64 * LDT];
  const int bm = blockIdx.y * 128, bn = blockIdx.x * 64;
  const int tid = threadIdx.x;
  const int lane = tid & 63, wv = tid >> 6;
  const int ra = tid >> 1, sa = (tid & 1) * 16;  // A: 2 thr/row, 16 f16 each
  const int rb = tid >> 2, sb = (tid & 3) * 8;   // B: 4 thr/row, 8 f16 each
  const int m_lo = lane & 15, koff = (lane >> 4) * 8, rq = lane >> 4;
  f32x4 acc[2][4] = {};
  for (int k0 = 0; k0 < K; k0 += 32) {
    const int4 zero4 = {0, 0, 0, 0};
    int gra = bm + ra;
    int4 a0 = (gra < M) ? *(const int4*)(A + (size_t)gra * K + k0 + sa) : zero4;
    int4 a1 = (gra < M) ? *(const int4*)(A + (size_t)gra * K + k0 + sa + 8) : zero4;
    int4 b0 = *(const int4*)(Bt + (size_t)(bn + rb) * K + k0 + sb);
    __syncthreads();
    *(int4*)(As + ra * LDT + sa) = a0;
    *(int4*)(As + ra * LDT + sa + 8) = a1;
    *(int4*)(Bs + rb * LDT + sb) = b0;
    __syncthreads();
    f16x8 af[2], bf[4];
    #pragma unroll
    for (int i = 0; i < 2; i++)
      af[i] = *(const f16x8*)(As + (wv * 32 + i * 16 + m_lo) * LDT + koff);
    #pragma unroll
    for (int j = 0; j < 4; j++)
      bf[j] = *(const f16x8*)(Bs + (j * 16 + m_lo) * LDT + koff);
    #pragma unroll
    for (int i = 0; i < 2; i++)
      #pragma unroll
      for (int j = 0; j < 4; j++)
        acc[i][j] = __builtin_amdgcn_mfma_f32_16x16x32_f16(af[i], bf[j], acc[i][j], 0, 0, 0);
  }
  #pragma unroll
  for (int i = 0; i < 2; i++)
    #pragma unroll
    for (int r = 0; r < 4; r++) {
      int grow = bm + wv * 32 + i * 16 + rq * 4 + r;
      if (grow < M)
        #pragma unroll
        for (int j = 0; j < 4; j++) {
          int gcol = bn + j * 16 + m_lo;
          C[(size_t)grow * N + gcol] = (_Float16)acc[i][j][r];
        }
    }
}

// ====== merged prep: zero cnt/pooled/cntg, transpose W1/W2, fold att =======
#define S0 N_NODES                 // cnt = 0
#define S1 (N_GRAPHS * HID)        // pooled = 0
#define S2 N_GRAPHS                // cntg = 0
#define S3 (IN_CH * HEADS * HID)   // W1T
#define S4 (HEADS * HID * HID)     // W2T
#define S5 (8 * IN_CH)             // wt1
#define S6 (HEADS * HID)           // wt2
#define PREP_TOTAL (S0 + S1 + S2 + S3 + S4 + S5 + S6)
__global__ void prep_kernel(const float* __restrict__ W1, const float* __restrict__ W2,
    const float* __restrict__ as1, const float* __restrict__ ad1,
    const float* __restrict__ as2, const float* __restrict__ ad2,
    int* __restrict__ cnt, float* __restrict__ pooled, float* __restrict__ cntg,
    _Float16* __restrict__ W1T, _Float16* __restrict__ W2T,
    float* __restrict__ wt1, float* __restrict__ wt2) {
  int idx = blockIdx.x * blockDim.x + threadIdx.x;
  if (idx < S0) { cnt[idx] = 0; return; }
  idx -= S0;
  if (idx < S1) { pooled[idx] = 0.f; return; }
  idx -= S1;
  if (idx < S2) { cntg[idx] = 0.f; return; }
  idx -= S2;
  if (idx < S3) {  // W1T[n*256+k] = W1[k*512+n]
    int n = idx >> 8, k = idx & 255;
    W1T[idx] = (_Float16)W1[(size_t)k * (HEADS * HID) + n];
    return;
  }
  idx -= S3;
  if (idx < S4) {  // W2T[n*512+k] = W2[k*128+n]
    int n = idx >> 9, k = idx & 511;
    W2T[idx] = (_Float16)W2[(size_t)k * HID + n];
    return;
  }
  idx -= S4;
  if (idx < S5) {  // wt1[j][i] = sum_c W1[i, h*128+c] * a{s,d}1[h][c]
    int j = idx >> 8, i = idx & 255;
    int sd = j >> 2, h = j & 3;
    const float* av = sd ? ad1 : as1;
    float s = 0.f;
    for (int c = 0; c < HID; ++c)
      s += W1[(size_t)i * (HEADS * HID) + h * HID + c] * av[h * HID + c];
    wt1[idx] = s;
    return;
  }
  idx -= S5;
  if (idx < S6) {  // wt2[0][c], wt2[1][c]
    float s = 0.f, d = 0.f;
    for (int j = 0; j < HID; ++j) {
      float w = W2[(size_t)idx * HID + j];
      s += w * as2[j];
      d += w * ad2[j];
    }
    wt2[idx] = s;
    wt2[HEADS * HID + idx] = d;
  }
}

// ====== x -> fp16 conversion fused with a1s/a1d = x @ wt1 (wave per node) ===
__global__ __launch_bounds__(256) void conv_x(const float* __restrict__ x,
    const float* __restrict__ wt1, _Float16* __restrict__ xb,
    float* __restrict__ a1s, float* __restrict__ a1d) {
  int node = blockIdx.x * 4 + (threadIdx.x >> 6);
  int lane = threadIdx.x & 63;
  if (node >= N_NODES) return;
  int c = lane * 4;
  float4 xv = *(const float4*)(x + (size_t)node * IN_CH + c);
  *(f16x4*)(xb + (size_t)node * IN_CH + c) =
      f16x4{(_Float16)xv.x, (_Float16)xv.y, (_Float16)xv.z, (_Float16)xv.w};
  float p[8];
  #pragma unroll
  for (int jj = 0; jj < 8; ++jj) {
    float4 w = *(const float4*)(wt1 + jj * IN_CH + c);
    p[jj] = xv.x * w.x + xv.y * w.y + xv.z * w.z + xv.w * w.w;
  }
  #pragma unroll
  for (int o = 32; o > 0; o >>= 1)
    #pragma unroll
    for (int jj = 0; jj < 8; ++jj) p[jj] += __shfl_down(p[jj], o);
  if (lane == 0) {
    #pragma unroll
    for (int h = 0; h < 4; ++h) {
      a1s[node * HEADS + h] = p[h];
      a1d[node * HEADS + h] = p[4 + h];
    }
  }
}

// ====== histogram by dst (with self loops) + per-graph node counts =========
__global__ void hist_kernel(const int* __restrict__ dst, const int* __restrict__ batch,
                            int* __restrict__ cnt, float* __restrict__ cntg) {
  int i = blockIdx.x * blockDim.x + threadIdx.x;
  if (i < ET) {
    int d = (i < N_EDGES) ? dst[i] : (i - N_EDGES);
    atomicAdd(&cnt[d], 1);
  } else if (i < ET + N_NODES) {
    atomicAdd(&cntg[batch[i - ET]], 1.0f);
  }
}

// ======================= exclusive scan, one block ==========================
#define SCH 20   // elements per thread: 1024*20 = 20480 >= 20000
__global__ __launch_bounds__(1024) void scan_kernel(const int* __restrict__ cnt,
    int* __restrict__ offs, int* __restrict__ cursor, int n) {
  int tid = threadIdx.x;
  int base = tid * SCH;
  int v[SCH];
  int s = 0;
  #pragma unroll
  for (int i = 0; i < SCH; i++) {
    int idx = base + i;
    int t = (idx < n) ? cnt[idx] : 0;
    v[i] = s; s += t;
  }
  int lane = tid & 63, wv = tid >> 6;   // 16 waves
  int x = s;
  #pragma unroll
  for (int o = 1; o < 64; o <<= 1) {
    int t = __shfl_up(x, o);
    if (lane >= o) x += t;
  }
  __shared__ int wsum[16];
  if (lane == 63) wsum[wv] = x;
  __syncthreads();
  if (tid == 0) {
    int r = 0;
    for (int w = 0; w < 16; w++) { int t = wsum[w]; wsum[w] = r; r += t; }
  }
  __syncthreads();
  int excl = x - s + wsum[wv];
  #pragma unroll
  for (int i = 0; i < SCH; i++) {
    int idx = base + i;
    if (idx < n) { offs[idx] = excl + v[i]; cursor[idx] = excl + v[i]; }
  }
  if (tid == 1023) offs[n] = excl + s;
}

__global__ void fill_kernel(const int* __restrict__ src, const int* __restrict__ dst,
                            int* __restrict__ cursor, int* __restrict__ csr) {
  int e = blockIdx.x * blockDim.x + threadIdx.x;
  if (e >= ET) return;
  int s, d;
  if (e < N_EDGES) { s = src[e]; d = dst[e]; } else { s = d = e - N_EDGES; }
  int pos = atomicAdd(&cursor[d], 1);
  csr[pos] = s;
}

// ====== layer-1 aggregation: 4 waves split edges, lane = 8 channels ========
// epilogue: relu + fp16 out + a2s/a2d fold via wt2
__global__ __launch_bounds__(256) void agg1_kernel(
    const _Float16* __restrict__ h1b, const float* __restrict__ a1s,
    const float* __restrict__ a1d, const int* __restrict__ offs,
    const int* __restrict__ csr, const float* __restrict__ b1,
    const float* __restrict__ wt2, _Float16* __restrict__ h1rb,
    float* __restrict__ a2s, float* __restrict__ a2d) {
  int n = blockIdx.x;
  int tid = threadIdx.x, lane = tid & 63, wv = tid >> 6;
  int head = lane >> 4;          // 16 lanes per head, 8 ch each
  int c0 = lane * 8;
  float ad_n = a1d[n * HEADS + head];
  float acc[8] = {};
  float den = 0.f;
  int e0 = offs[n], e1 = offs[n + 1];
  int e = e0 + wv;
  int s = (e < e1) ? csr[e] : 0;
  while (e < e1) {
    int en = e + 4;
    int sn = (en < e1) ? csr[en] : 0;          // prefetch next src
    float aa = a1s[s * HEADS + head] + ad_n;
    aa = (aa > 0.f) ? aa : NEG_SLOPE * aa;
    float al = __expf(aa);
    f16x8 hv = *(const f16x8*)(h1b + (size_t)s * (HEADS * HID) + c0);
    #pragma unroll
    for (int i = 0; i < 8; i++) acc[i] += al * (float)hv[i];
    den += al;
    e = en; s = sn;
  }
  __shared__ float lacc[4][HEADS * HID];
  __shared__ float lden[4][HEADS];
  __shared__ float rs[4], rd[4];
  #pragma unroll
  for (int i = 0; i < 8; i++) lacc[wv][c0 + i] = acc[i];
  if ((lane & 15) == 0) lden[wv][head] = den;
  __syncthreads();
  int c = tid * 2;
  int hd = c >> 7;
  float s0 = lacc[0][c] + lacc[1][c] + lacc[2][c] + lacc[3][c];
  float s1 = lacc[0][c + 1] + lacc[1][c + 1] + lacc[2][c + 1] + lacc[3][c + 1];
  float dtot = lden[0][hd] + lden[1][hd] + lden[2][hd] + lden[3][hd];
  float inv = 1.f / dtot;
  float o0 = fmaxf(s0 * inv + b1[c], 0.f);
  float o1 = fmaxf(s1 * inv + b1[c + 1], 0.f);
  *(f16x2*)(h1rb + (size_t)n * (HEADS * HID) + c) = f16x2{(_Float16)o0, (_Float16)o1};
  // layer-2 attention coefficients (fold: h2.as2 = h1r.(W2@as2))
  float ps = o0 * wt2[c] + o1 * wt2[c + 1];
  float pd = o0 * wt2[HEADS * HID + c] + o1 * wt2[HEADS * HID + c + 1];
  #pragma unroll
  for (int o = 32; o > 0; o >>= 1) { ps += __shfl_down(ps, o); pd += __shfl_down(pd, o); }
  if (lane == 0) { rs[wv] = ps; rd[wv] = pd; }
  __syncthreads();
  if (tid == 0) a2s[n] = rs[0] + rs[1] + rs[2] + rs[3];
  if (tid == 1) a2d[n] = rd[0] + rd[1] + rd[2] + rd[3];
}

// ==== layer-2 aggregation (4 waves split edges) + global mean-pool fuse ====
__global__ __launch_bounds__(256) void agg2_pool(
    const _Float16* __restrict__ h2b, const float* __restrict__ a2s,
    const float* __restrict__ a2d, const int* __restrict__ offs,
    const int* __restrict__ csr, const float* __restrict__ b2,
    const int* __restrict__ batch, float* __restrict__ pooled) {
  int n = blockIdx.x;
  int tid = threadIdx.x, lane = tid & 63, wv = tid >> 6;
  int c0 = lane * 2;
  float ad_n = a2d[n];
  float acc0 = 0.f, acc1 = 0.f, den = 0.f;
  int e0 = offs[n], e1 = offs[n + 1];
  int e = e0 + wv;
  int s = (e < e1) ? csr[e] : 0;
  while (e < e1) {
    int en = e + 4;
    int sn = (en < e1) ? csr[en] : 0;
    float aa = a2s[s] + ad_n;
    aa = (aa > 0.f) ? aa : NEG_SLOPE * aa;
    float al = __expf(aa);
    f16x2 hv = *(const f16x2*)(h2b + (size_t)s * HID + c0);
    acc0 += al * (float)hv.x;
    acc1 += al * (float)hv.y;
    den += al;
    e = en; s = sn;
  }
  __shared__ float lacc[4][HID];
  __shared__ float lden[4];
  lacc[wv][c0] = acc0; lacc[wv][c0 + 1] = acc1;
  if (lane == 0) lden[wv] = den;
  __syncthreads();
  if (tid < 64) {
    int c = tid * 2;
    float s0 = lacc[0][c] + lacc[1][c] + lacc[2][c] + lacc[3][c];
    float s1 = lacc[0][c + 1] + lacc[1][c + 1] + lacc[2][c + 1] + lacc[3][c + 1];
    float dt = lden[0] + lden[1] + lden[2] + lden[3];
    float inv = 1.f / dt;
    int g = batch[n];
    atomicAdd(&pooled[g * HID + c], s0 * inv + b2[c]);
    atomicAdd(&pooled[g * HID + c + 1], s1 * inv + b2[c + 1]);
  }
}

// ------------------------------ MLP head ------------------------------------
__global__ __launch_bounds__(128) void mlp_kernel(const float* __restrict__ pooled,
    const float* __restrict__ cntg, const float* __restrict__ Wm1,
    const float* __restrict__ bm1, const float* __restrict__ Wm2,
    const float* __restrict__ bm2, float* __restrict__ outp) {
  __shared__ float pl[HID];
  __shared__ float z[HID];
  int g = blockIdx.x, j = threadIdx.x;
  float inv = 1.f / fmaxf(cntg[g], 1.f);
  pl[j] = pooled[g * HID + j] * inv;
  __syncthreads();
  float s = bm1[j];
  for (int k = 0; k < HID; ++k) s += pl[k] * Wm1[k * HID + j];
  z[j] = fmaxf(s, 0.f);
  __syncthreads();
  if (j < OUT_CH) {
    float o = bm2[j];
    for (int k = 0; k < HID; ++k) o += z[k] * Wm2[k * OUT_CH + j];
    outp[g * OUT_CH + j] = o;
  }
}

extern "C" void kernel_launch(void* const* d_in, const int* in_sizes, int n_in,
                              void* d_out, int out_size, void* d_ws, size_t ws_size,
                              hipStream_t stream) {
  const float* x    = (const float*)d_in[0];
  const int*   ei   = (const int*)d_in[1];
  const int*   batch= (const int*)d_in[2];
  const float* W1   = (const float*)d_in[3];
  const float* as1  = (const float*)d_in[4];
  const float* ad1  = (const float*)d_in[5];
  const float* b1   = (const float*)d_in[6];
  const float* W2   = (const float*)d_in[7];
  const float* as2  = (const float*)d_in[8];
  const float* ad2  = (const float*)d_in[9];
  const float* b2   = (const float*)d_in[10];
  const float* Wm1  = (const float*)d_in[11];
  const float* bm1  = (const float*)d_in[12];
  const float* Wm2  = (const float*)d_in[13];
  const float* bm2  = (const float*)d_in[14];
  float* outp = (float*)d_out;
  const int* srcp = ei;
  const int* dstp = ei + N_EDGES;

  // ---- workspace carve-up ----
  char* p = (char*)d_ws;
  auto alloc = [&](size_t bytes) {
    char* r = p; p += (bytes + 255) & ~(size_t)255; return r;
  };
  _Float16* xb   = (_Float16*)alloc((size_t)N_NODES * IN_CH * 2);
  _Float16* h1b  = (_Float16*)alloc((size_t)N_NODES * HEADS * HID * 2);
  _Float16* h1rb = (_Float16*)alloc((size_t)N_NODES * HEADS * HID * 2);
  _Float16* h2b  = (_Float16*)alloc((size_t)N_NODES * HID * 2);
  _Float16* W1T  = (_Float16*)alloc((size_t)(HEADS * HID) * IN_CH * 2);
  _Float16* W2T  = (_Float16*)alloc((size_t)HID * (HEADS * HID) * 2);
  float* wt1     = (float*)alloc(8 * IN_CH * 4);
  float* wt2     = (float*)alloc(2 * (HEADS * HID) * 4);
  float* a1s     = (float*)alloc((size_t)N_NODES * HEADS * 4);
  float* a1d     = (float*)alloc((size_t)N_NODES * HEADS * 4);
  float* a2s     = (float*)alloc((size_t)N_NODES * 4);
  float* a2d     = (float*)alloc((size_t)N_NODES * 4);
  int*   cnt     = (int*)alloc((size_t)N_NODES * 4);
  int*   offs    = (int*)alloc((size_t)(N_NODES + 1) * 4);
  int*   cursor  = (int*)alloc((size_t)N_NODES * 4);
  int*   csr     = (int*)alloc((size_t)ET * 4);
  float* pooled  = (float*)alloc((size_t)N_GRAPHS * HID * 4);
  float* cntg    = (float*)alloc((size_t)N_GRAPHS * 4);

  // one fused prep kernel: zeros + weight transposes + attention-vector folds
  prep_kernel<<<(PREP_TOTAL + 255) / 256, 256, 0, stream>>>(
      W1, W2, as1, ad1, as2, ad2, cnt, pooled, cntg, W1T, W2T, wt1, wt2);

  conv_x<<<(N_NODES + 3) / 4, 256, 0, stream>>>(x, wt1, xb, a1s, a1d);

  hist_kernel<<<(ET + N_NODES + 255) / 256, 256, 0, stream>>>(dstp, batch, cnt, cntg);
  scan_kernel<<<1, 1024, 0, stream>>>(cnt, offs, cursor, N_NODES);
  fill_kernel<<<(ET + 255) / 256, 256, 0, stream>>>(srcp, dstp, cursor, csr);

  gemm_f16<<<dim3((HEADS * HID) / 128, (N_NODES + 127) / 128), 256, 0, stream>>>(
      xb, W1T, h1b, N_NODES, HEADS * HID, IN_CH);

  agg1_kernel<<<N_NODES, 256, 0, stream>>>(h1b, a1s, a1d, offs, csr, b1, wt2, h1rb, a2s, a2d);

  gemm2_f16<<<dim3(HID / 64, (N_NODES + 127) / 128), 256, 0, stream>>>(
      h1rb, W2T, h2b, N_NODES, HID, HEADS * HID);

  agg2_pool<<<N_NODES, 256, 0, stream>>>(h2b, a2s, a2d, offs, csr, b2, batch, pooled);

  mlp_kernel<<<N_GRAPHS, HID, 0, stream>>>(pooled, cntg, Wm1, bm1, Wm2, bm2, outp);
}

// Round 4
// 317.323 us; speedup vs baseline: 2.0095x; 1.1880x over previous
//
#include <hip/hip_runtime.h>
#include <math.h>

#define N_NODES 20000
#define N_EDGES 320000
#define ET (N_EDGES + N_NODES)   // edges + self loops
#define IN_CH 256
#define HID 128
#define HEADS 4
#define OUT_CH 16
#define N_GRAPHS 128
#define NEG_SLOPE 0.2f

typedef _Float16 f16x8 __attribute__((ext_vector_type(8)));
typedef _Float16 f16x4 __attribute__((ext_vector_type(4)));
typedef _Float16 f16x2 __attribute__((ext_vector_type(2)));
typedef float f32x4 __attribute__((ext_vector_type(4)));

// =============== fp16 MFMA GEMM: C[M,N] = A[M,K] @ Bt[N,K]^T ================
// 128x128 tile, BK=32, 4 waves of 4x4 16x16x32 MFMA tiles.
#define LDT 40   // padded LDS stride in f16 (80 B: 16B-aligned, 2-way max conflict)
__global__ __launch_bounds__(256) void gemm_f16(const _Float16* __restrict__ A,
    const _Float16* __restrict__ Bt, _Float16* __restrict__ C,
    int M, int N, int K) {
  __shared__ _Float16 As[128 * LDT];
  __shared__ _Float16 Bs[128 * LDT];
  const int bm = blockIdx.y * 128, bn = blockIdx.x * 128;
  const int tid = threadIdx.x;
  const int lane = tid & 63, wv = tid >> 6;
  const int wr = wv >> 1, wc = wv & 1;
  const int r0 = tid >> 2, seg = tid & 3;
  const int m_lo = lane & 15, koff = (lane >> 4) * 8, rq = lane >> 4;
  f32x4 acc[4][4] = {};
  for (int k0 = 0; k0 < K; k0 += 32) {
    const int4 zero4 = {0, 0, 0, 0};
    int gr0 = bm + r0, gr1 = bm + r0 + 64;
    int4 av0 = (gr0 < M) ? *(const int4*)(A + (size_t)gr0 * K + k0 + seg * 8) : zero4;
    int4 av1 = (gr1 < M) ? *(const int4*)(A + (size_t)gr1 * K + k0 + seg * 8) : zero4;
    int4 bv0 = *(const int4*)(Bt + (size_t)(bn + r0) * K + k0 + seg * 8);
    int4 bv1 = *(const int4*)(Bt + (size_t)(bn + r0 + 64) * K + k0 + seg * 8);
    __syncthreads();
    *(int4*)(As + r0 * LDT + seg * 8) = av0;
    *(int4*)(As + (r0 + 64) * LDT + seg * 8) = av1;
    *(int4*)(Bs + r0 * LDT + seg * 8) = bv0;
    *(int4*)(Bs + (r0 + 64) * LDT + seg * 8) = bv1;
    __syncthreads();
    f16x8 af[4], bf[4];
    #pragma unroll
    for (int i = 0; i < 4; i++)
      af[i] = *(const f16x8*)(As + (wr * 64 + i * 16 + m_lo) * LDT + koff);
    #pragma unroll
    for (int j = 0; j < 4; j++)
      bf[j] = *(const f16x8*)(Bs + (wc * 64 + j * 16 + m_lo) * LDT + koff);
    #pragma unroll
    for (int i = 0; i < 4; i++)
      #pragma unroll
      for (int j = 0; j < 4; j++)
        acc[i][j] = __builtin_amdgcn_mfma_f32_16x16x32_f16(af[i], bf[j], acc[i][j], 0, 0, 0);
  }
  // C/D layout: col = lane&15, row = (lane>>4)*4 + reg
  #pragma unroll
  for (int i = 0; i < 4; i++)
    #pragma unroll
    for (int r = 0; r < 4; r++) {
      int grow = bm + wr * 64 + i * 16 + rq * 4 + r;
      if (grow < M)
        #pragma unroll
        for (int j = 0; j < 4; j++) {
          int gcol = bn + wc * 64 + j * 16 + m_lo;
          C[(size_t)grow * N + gcol] = (_Float16)acc[i][j][r];
        }
    }
}

// ============== fp16 MFMA GEMM, 128x64 tile (for N=128 layer-2) =============
__global__ __launch_bounds__(256) void gemm2_f16(const _Float16* __restrict__ A,
    const _Float16* __restrict__ Bt, _Float16* __restrict__ C,
    int M, int N, int K) {
  __shared__ _Float16 As[128 * LDT];
  __shared__ _Float16 Bs[64 * LDT];
  const int bm = blockIdx.y * 128, bn = blockIdx.x * 64;
  const int tid = threadIdx.x;
  const int lane = tid & 63, wv = tid >> 6;
  const int ra = tid >> 1, sa = (tid & 1) * 16;  // A: 2 thr/row, 16 f16 each
  const int rb = tid >> 2, sb = (tid & 3) * 8;   // B: 4 thr/row, 8 f16 each
  const int m_lo = lane & 15, koff = (lane >> 4) * 8, rq = lane >> 4;
  f32x4 acc[2][4] = {};
  for (int k0 = 0; k0 < K; k0 += 32) {
    const int4 zero4 = {0, 0, 0, 0};
    int gra = bm + ra;
    int4 a0 = (gra < M) ? *(const int4*)(A + (size_t)gra * K + k0 + sa) : zero4;
    int4 a1 = (gra < M) ? *(const int4*)(A + (size_t)gra * K + k0 + sa + 8) : zero4;
    int4 b0 = *(const int4*)(Bt + (size_t)(bn + rb) * K + k0 + sb);
    __syncthreads();
    *(int4*)(As + ra * LDT + sa) = a0;
    *(int4*)(As + ra * LDT + sa + 8) = a1;
    *(int4*)(Bs + rb * LDT + sb) = b0;
    __syncthreads();
    f16x8 af[2], bf[4];
    #pragma unroll
    for (int i = 0; i < 2; i++)
      af[i] = *(const f16x8*)(As + (wv * 32 + i * 16 + m_lo) * LDT + koff);
    #pragma unroll
    for (int j = 0; j < 4; j++)
      bf[j] = *(const f16x8*)(Bs + (j * 16 + m_lo) * LDT + koff);
    #pragma unroll
    for (int i = 0; i < 2; i++)
      #pragma unroll
      for (int j = 0; j < 4; j++)
        acc[i][j] = __builtin_amdgcn_mfma_f32_16x16x32_f16(af[i], bf[j], acc[i][j], 0, 0, 0);
  }
  #pragma unroll
  for (int i = 0; i < 2; i++)
    #pragma unroll
    for (int r = 0; r < 4; r++) {
      int grow = bm + wv * 32 + i * 16 + rq * 4 + r;
      if (grow < M)
        #pragma unroll
        for (int j = 0; j < 4; j++) {
          int gcol = bn + j * 16 + m_lo;
          C[(size_t)grow * N + gcol] = (_Float16)acc[i][j][r];
        }
    }
}

// ====== merged prep: zero cnt, transpose W1/W2 to fp16, fold att vectors ====
#define S0 N_NODES                 // cnt = 0
#define S1 (IN_CH * HEADS * HID)   // W1T
#define S2 (HEADS * HID * HID)     // W2T
#define S3 (8 * IN_CH)             // wt1
#define S4 (HEADS * HID)           // wt2
#define PREP_TOTAL (S0 + S1 + S2 + S3 + S4)
__global__ void prep_kernel(const float* __restrict__ W1, const float* __restrict__ W2,
    const float* __restrict__ as1, const float* __restrict__ ad1,
    const float* __restrict__ as2, const float* __restrict__ ad2,
    int* __restrict__ cnt,
    _Float16* __restrict__ W1T, _Float16* __restrict__ W2T,
    float* __restrict__ wt1, float* __restrict__ wt2) {
  int idx = blockIdx.x * blockDim.x + threadIdx.x;
  if (idx < S0) { cnt[idx] = 0; return; }
  idx -= S0;
  if (idx < S1) {  // W1T[n*256+k] = W1[k*512+n]
    int n = idx >> 8, k = idx & 255;
    W1T[idx] = (_Float16)W1[(size_t)k * (HEADS * HID) + n];
    return;
  }
  idx -= S1;
  if (idx < S2) {  // W2T[n*512+k] = W2[k*128+n]
    int n = idx >> 9, k = idx & 511;
    W2T[idx] = (_Float16)W2[(size_t)k * HID + n];
    return;
  }
  idx -= S2;
  if (idx < S3) {  // wt1[j][i] = sum_c W1[i, h*128+c] * a{s,d}1[h][c]
    int j = idx >> 8, i = idx & 255;
    int sd = j >> 2, h = j & 3;
    const float* av = sd ? ad1 : as1;
    float s = 0.f;
    for (int c = 0; c < HID; ++c)
      s += W1[(size_t)i * (HEADS * HID) + h * HID + c] * av[h * HID + c];
    wt1[idx] = s;
    return;
  }
  idx -= S3;
  if (idx < S4) {  // wt2[0][c], wt2[1][c]
    float s = 0.f, d = 0.f;
    for (int j = 0; j < HID; ++j) {
      float w = W2[(size_t)idx * HID + j];
      s += w * as2[j];
      d += w * ad2[j];
    }
    wt2[idx] = s;
    wt2[HEADS * HID + idx] = d;
  }
}

// ====== x -> fp16 conversion fused with a1s/a1d = x @ wt1 (wave per node) ===
__global__ __launch_bounds__(256) void conv_x(const float* __restrict__ x,
    const float* __restrict__ wt1, _Float16* __restrict__ xb,
    float* __restrict__ a1s, float* __restrict__ a1d) {
  int node = blockIdx.x * 4 + (threadIdx.x >> 6);
  int lane = threadIdx.x & 63;
  if (node >= N_NODES) return;
  int c = lane * 4;
  float4 xv = *(const float4*)(x + (size_t)node * IN_CH + c);
  *(f16x4*)(xb + (size_t)node * IN_CH + c) =
      f16x4{(_Float16)xv.x, (_Float16)xv.y, (_Float16)xv.z, (_Float16)xv.w};
  float p[8];
  #pragma unroll
  for (int jj = 0; jj < 8; ++jj) {
    float4 w = *(const float4*)(wt1 + jj * IN_CH + c);
    p[jj] = xv.x * w.x + xv.y * w.y + xv.z * w.z + xv.w * w.w;
  }
  #pragma unroll
  for (int o = 32; o > 0; o >>= 1)
    #pragma unroll
    for (int jj = 0; jj < 8; ++jj) p[jj] += __shfl_down(p[jj], o);
  if (lane == 0) {
    #pragma unroll
    for (int h = 0; h < 4; ++h) {
      a1s[node * HEADS + h] = p[h];
      a1d[node * HEADS + h] = p[4 + h];
    }
  }
}

// == histogram by dst (int atomics, random addrs) + graph bounds (bsearch) ==
__global__ void hist_kernel(const int* __restrict__ dst, const int* __restrict__ batch,
                            int* __restrict__ cnt, int* __restrict__ goff) {
  int i = blockIdx.x * blockDim.x + threadIdx.x;
  if (i < ET) {
    int d = (i < N_EDGES) ? dst[i] : (i - N_EDGES);
    atomicAdd(&cnt[d], 1);
  } else if (i < ET + N_GRAPHS + 1) {
    // batch is sorted: goff[g] = lower_bound(batch, g) — no atomics
    int g = i - ET;
    int lo = 0, hi = N_NODES;
    while (lo < hi) {
      int mid = (lo + hi) >> 1;
      if (batch[mid] < g) lo = mid + 1; else hi = mid;
    }
    goff[g] = lo;
  }
}

// ======================= exclusive scan, one block ==========================
#define SCH 20   // elements per thread: 1024*20 = 20480 >= 20000
__global__ __launch_bounds__(1024) void scan_kernel(const int* __restrict__ cnt,
    int* __restrict__ offs, int* __restrict__ cursor, int n) {
  int tid = threadIdx.x;
  int base = tid * SCH;
  int v[SCH];
  int s = 0;
  #pragma unroll
  for (int i = 0; i < SCH; i++) {
    int idx = base + i;
    int t = (idx < n) ? cnt[idx] : 0;
    v[i] = s; s += t;
  }
  int lane = tid & 63, wv = tid >> 6;   // 16 waves
  int x = s;
  #pragma unroll
  for (int o = 1; o < 64; o <<= 1) {
    int t = __shfl_up(x, o);
    if (lane >= o) x += t;
  }
  __shared__ int wsum[16];
  if (lane == 63) wsum[wv] = x;
  __syncthreads();
  if (tid == 0) {
    int r = 0;
    for (int w = 0; w < 16; w++) { int t = wsum[w]; wsum[w] = r; r += t; }
  }
  __syncthreads();
  int excl = x - s + wsum[wv];
  #pragma unroll
  for (int i = 0; i < SCH; i++) {
    int idx = base + i;
    if (idx < n) { offs[idx] = excl + v[i]; cursor[idx] = excl + v[i]; }
  }
  if (tid == 1023) offs[n] = excl + s;
}

__global__ void fill_kernel(const int* __restrict__ src, const int* __restrict__ dst,
                            int* __restrict__ cursor, int* __restrict__ csr) {
  int e = blockIdx.x * blockDim.x + threadIdx.x;
  if (e >= ET) return;
  int s, d;
  if (e < N_EDGES) { s = src[e]; d = dst[e]; } else { s = d = e - N_EDGES; }
  int pos = atomicAdd(&cursor[d], 1);
  csr[pos] = s;
}

// ====== layer-1 aggregation: 4 waves split edges, lane = 8 channels ========
// epilogue: relu + fp16 out + a2s/a2d fold via wt2
__global__ __launch_bounds__(256) void agg1_kernel(
    const _Float16* __restrict__ h1b, const float* __restrict__ a1s,
    const float* __restrict__ a1d, const int* __restrict__ offs,
    const int* __restrict__ csr, const float* __restrict__ b1,
    const float* __restrict__ wt2, _Float16* __restrict__ h1rb,
    float* __restrict__ a2s, float* __restrict__ a2d) {
  int n = blockIdx.x;
  int tid = threadIdx.x, lane = tid & 63, wv = tid >> 6;
  int head = lane >> 4;          // 16 lanes per head, 8 ch each
  int c0 = lane * 8;
  float ad_n = a1d[n * HEADS + head];
  float acc[8] = {};
  float den = 0.f;
  int e0 = offs[n], e1 = offs[n + 1];
  int e = e0 + wv;
  int s = (e < e1) ? csr[e] : 0;
  while (e < e1) {
    int en = e + 4;
    int sn = (en < e1) ? csr[en] : 0;          // prefetch next src
    float aa = a1s[s * HEADS + head] + ad_n;
    aa = (aa > 0.f) ? aa : NEG_SLOPE * aa;
    float al = __expf(aa);
    f16x8 hv = *(const f16x8*)(h1b + (size_t)s * (HEADS * HID) + c0);
    #pragma unroll
    for (int i = 0; i < 8; i++) acc[i] += al * (float)hv[i];
    den += al;
    e = en; s = sn;
  }
  __shared__ float lacc[4][HEADS * HID];
  __shared__ float lden[4][HEADS];
  __shared__ float rs[4], rd[4];
  #pragma unroll
  for (int i = 0; i < 8; i++) lacc[wv][c0 + i] = acc[i];
  if ((lane & 15) == 0) lden[wv][head] = den;
  __syncthreads();
  int c = tid * 2;
  int hd = c >> 7;
  float s0 = lacc[0][c] + lacc[1][c] + lacc[2][c] + lacc[3][c];
  float s1 = lacc[0][c + 1] + lacc[1][c + 1] + lacc[2][c + 1] + lacc[3][c + 1];
  float dtot = lden[0][hd] + lden[1][hd] + lden[2][hd] + lden[3][hd];
  float inv = 1.f / dtot;
  float o0 = fmaxf(s0 * inv + b1[c], 0.f);
  float o1 = fmaxf(s1 * inv + b1[c + 1], 0.f);
  *(f16x2*)(h1rb + (size_t)n * (HEADS * HID) + c) = f16x2{(_Float16)o0, (_Float16)o1};
  // layer-2 attention coefficients (fold: h2.as2 = h1r.(W2@as2))
  float ps = o0 * wt2[c] + o1 * wt2[c + 1];
  float pd = o0 * wt2[HEADS * HID + c] + o1 * wt2[HEADS * HID + c + 1];
  #pragma unroll
  for (int o = 32; o > 0; o >>= 1) { ps += __shfl_down(ps, o); pd += __shfl_down(pd, o); }
  if (lane == 0) { rs[wv] = ps; rd[wv] = pd; }
  __syncthreads();
  if (tid == 0) a2s[n] = rs[0] + rs[1] + rs[2] + rs[3];
  if (tid == 1) a2d[n] = rd[0] + rd[1] + rd[2] + rd[3];
}

// ==== layer-2 aggregation (4 waves split edges), coalesced fp32 output =====
__global__ __launch_bounds__(256) void agg2_kernel(
    const _Float16* __restrict__ h2b, const float* __restrict__ a2s,
    const float* __restrict__ a2d, const int* __restrict__ offs,
    const int* __restrict__ csr, const float* __restrict__ b2,
    float* __restrict__ h2a) {
  int n = blockIdx.x;
  int tid = threadIdx.x, lane = tid & 63, wv = tid >> 6;
  int c0 = lane * 2;
  float ad_n = a2d[n];
  float acc0 = 0.f, acc1 = 0.f, den = 0.f;
  int e0 = offs[n], e1 = offs[n + 1];
  int e = e0 + wv;
  int s = (e < e1) ? csr[e] : 0;
  while (e < e1) {
    int en = e + 4;
    int sn = (en < e1) ? csr[en] : 0;
    float aa = a2s[s] + ad_n;
    aa = (aa > 0.f) ? aa : NEG_SLOPE * aa;
    float al = __expf(aa);
    f16x2 hv = *(const f16x2*)(h2b + (size_t)s * HID + c0);
    acc0 += al * (float)hv.x;
    acc1 += al * (float)hv.y;
    den += al;
    e = en; s = sn;
  }
  __shared__ float lacc[4][HID];
  __shared__ float lden[4];
  lacc[wv][c0] = acc0; lacc[wv][c0 + 1] = acc1;
  if (lane == 0) lden[wv] = den;
  __syncthreads();
  if (tid < 64) {
    int c = tid * 2;
    float s0 = lacc[0][c] + lacc[1][c] + lacc[2][c] + lacc[3][c];
    float s1 = lacc[0][c + 1] + lacc[1][c + 1] + lacc[2][c + 1] + lacc[3][c + 1];
    float dt = lden[0] + lden[1] + lden[2] + lden[3];
    float inv = 1.f / dt;
    *(float2*)&h2a[(size_t)n * HID + c] =
        make_float2(s0 * inv + b2[c], s1 * inv + b2[c + 1]);
  }
}

// ====== fused mean-pool (contiguous node ranges) + 2-layer MLP head ========
// one block per graph; batch sorted so nodes [goff[g], goff[g+1]) are graph g
__global__ __launch_bounds__(256) void pool_mlp(const float* __restrict__ h2a,
    const int* __restrict__ goff, const float* __restrict__ Wm1,
    const float* __restrict__ bm1, const float* __restrict__ Wm2,
    const float* __restrict__ bm2, float* __restrict__ outp) {
  __shared__ float part[2][HID];
  __shared__ float pl[HID];
  __shared__ float z[HID];
  int g = blockIdx.x, tid = threadIdx.x;
  int c = tid & 127, half = tid >> 7;
  int n0 = goff[g], n1 = goff[g + 1];
  float acc = 0.f;
  for (int n = n0 + half; n < n1; n += 2)
    acc += h2a[(size_t)n * HID + c];
  part[half][c] = acc;
  __syncthreads();
  if (tid < HID) {
    float inv = 1.f / fmaxf((float)(n1 - n0), 1.f);
    pl[tid] = (part[0][tid] + part[1][tid]) * inv;
  }
  __syncthreads();
  if (tid < HID) {
    float s = bm1[tid];
    for (int k = 0; k < HID; ++k) s += pl[k] * Wm1[k * HID + tid];
    z[tid] = fmaxf(s, 0.f);
  }
  __syncthreads();
  if (tid < OUT_CH) {
    float o = bm2[tid];
    for (int k = 0; k < HID; ++k) o += z[k] * Wm2[k * OUT_CH + tid];
    outp[g * OUT_CH + tid] = o;
  }
}

extern "C" void kernel_launch(void* const* d_in, const int* in_sizes, int n_in,
                              void* d_out, int out_size, void* d_ws, size_t ws_size,
                              hipStream_t stream) {
  const float* x    = (const float*)d_in[0];
  const int*   ei   = (const int*)d_in[1];
  const int*   batch= (const int*)d_in[2];
  const float* W1   = (const float*)d_in[3];
  const float* as1  = (const float*)d_in[4];
  const float* ad1  = (const float*)d_in[5];
  const float* b1   = (const float*)d_in[6];
  const float* W2   = (const float*)d_in[7];
  const float* as2  = (const float*)d_in[8];
  const float* ad2  = (const float*)d_in[9];
  const float* b2   = (const float*)d_in[10];
  const float* Wm1  = (const float*)d_in[11];
  const float* bm1  = (const float*)d_in[12];
  const float* Wm2  = (const float*)d_in[13];
  const float* bm2  = (const float*)d_in[14];
  float* outp = (float*)d_out;
  const int* srcp = ei;
  const int* dstp = ei + N_EDGES;

  // ---- workspace carve-up ----
  char* p = (char*)d_ws;
  auto alloc = [&](size_t bytes) {
    char* r = p; p += (bytes + 255) & ~(size_t)255; return r;
  };
  _Float16* xb   = (_Float16*)alloc((size_t)N_NODES * IN_CH * 2);
  _Float16* h1b  = (_Float16*)alloc((size_t)N_NODES * HEADS * HID * 2);
  _Float16* h1rb = (_Float16*)alloc((size_t)N_NODES * HEADS * HID * 2);
  _Float16* h2b  = (_Float16*)alloc((size_t)N_NODES * HID * 2);
  float*    h2a  = (float*)alloc((size_t)N_NODES * HID * 4);
  _Float16* W1T  = (_Float16*)alloc((size_t)(HEADS * HID) * IN_CH * 2);
  _Float16* W2T  = (_Float16*)alloc((size_t)HID * (HEADS * HID) * 2);
  float* wt1     = (float*)alloc(8 * IN_CH * 4);
  float* wt2     = (float*)alloc(2 * (HEADS * HID) * 4);
  float* a1s     = (float*)alloc((size_t)N_NODES * HEADS * 4);
  float* a1d     = (float*)alloc((size_t)N_NODES * HEADS * 4);
  float* a2s     = (float*)alloc((size_t)N_NODES * 4);
  float* a2d     = (float*)alloc((size_t)N_NODES * 4);
  int*   cnt     = (int*)alloc((size_t)N_NODES * 4);
  int*   offs    = (int*)alloc((size_t)(N_NODES + 1) * 4);
  int*   cursor  = (int*)alloc((size_t)N_NODES * 4);
  int*   csr     = (int*)alloc((size_t)ET * 4);
  int*   goff    = (int*)alloc((size_t)(N_GRAPHS + 1) * 4);

  prep_kernel<<<(PREP_TOTAL + 255) / 256, 256, 0, stream>>>(
      W1, W2, as1, ad1, as2, ad2, cnt, W1T, W2T, wt1, wt2);

  conv_x<<<(N_NODES + 3) / 4, 256, 0, stream>>>(x, wt1, xb, a1s, a1d);

  hist_kernel<<<(ET + N_GRAPHS + 1 + 255) / 256, 256, 0, stream>>>(dstp, batch, cnt, goff);
  scan_kernel<<<1, 1024, 0, stream>>>(cnt, offs, cursor, N_NODES);
  fill_kernel<<<(ET + 255) / 256, 256, 0, stream>>>(srcp, dstp, cursor, csr);

  gemm_f16<<<dim3((HEADS * HID) / 128, (N_NODES + 127) / 128), 256, 0, stream>>>(
      xb, W1T, h1b, N_NODES, HEADS * HID, IN_CH);

  agg1_kernel<<<N_NODES, 256, 0, stream>>>(h1b, a1s, a1d, offs, csr, b1, wt2, h1rb, a2s, a2d);

  gemm2_f16<<<dim3(HID / 64, (N_NODES + 127) / 128), 256, 0, stream>>>(
      h1rb, W2T, h2b, N_NODES, HID, HEADS * HID);

  agg2_kernel<<<N_NODES, 256, 0, stream>>>(h2b, a2s, a2d, offs, csr, b2, h2a);

  pool_mlp<<<N_GRAPHS, 256, 0, stream>>>(h2a, goff, Wm1, bm1, Wm2, bm2, outp);
}